// Round 4
// baseline (195.249 us; speedup 1.0000x reference)
//
#include <hip/hip_runtime.h>
#include <hip/hip_bf16.h>

// Sparse conv gather->GEMM->scatter for MI355X (gfx950), 2-phase:
//   K2': per-offset MFMA GEMM (software-pipelined gather) -> vals[pair][64] bf16
//        + fused histogram/slot-table build placed AFTER the MFMA loop
//   K3 : per-row segmented reduce over slot list -> out (single write per row)
// Fallback to a pure-atomic kernel if ws_size is insufficient.

typedef __bf16 bf16x8 __attribute__((ext_vector_type(8)));
typedef __bf16 bf16x4 __attribute__((ext_vector_type(4)));
typedef float f32x4 __attribute__((ext_vector_type(4)));

#define KOFF 27
#define CAP 64
#define WPAD 72  // 64 + 8 pad: wfrag ds_read_b128 16-way conflict -> 2-way (free)

// ---- K2': per-offset GEMM + end-of-wave hist, vals (bf16) to ws ----
// Swapped-operand mfma: D[ch][pair]; lane (g,r) owns pair base+r, channels t*16+g*4+{0..3}.
template <int ITER>
__global__ __launch_bounds__(256) void k2_gemm_hist(
    const float* __restrict__ feat, const float* __restrict__ kern,
    const int* __restrict__ nin, const int* __restrict__ nout,
    int* __restrict__ counts, int* __restrict__ slots,
    __bf16* __restrict__ vals, int Lpairs, int blocksPerK, int cshift) {
  __shared__ __bf16 ldsBT[64 * WPAD];  // ldsBT[c*WPAD+i] = W[i][c]
  const int bk = blockIdx.x / blocksPerK;
  const int chunk = blockIdx.x % blocksPerK;
  const float* kb = kern + bk * 4096;
  for (int idx = threadIdx.x; idx < 4096; idx += 256) {
    int i = idx >> 6, c = idx & 63;
    ldsBT[c * WPAD + i] = (__bf16)kb[idx];
  }
  __syncthreads();

  const int lane = threadIdx.x & 63;
  const int wave = threadIdx.x >> 6;
  const int r = lane & 15, g = lane >> 4;

  // W fragment (A operand): A[m=r][k=g*8+s*32+j]
  bf16x8 wfrag[2][4];
#pragma unroll
  for (int s = 0; s < 2; ++s)
#pragma unroll
    for (int t = 0; t < 4; ++t)
      wfrag[s][t] = *(const bf16x8*)&ldsBT[(t * 16 + r) * WPAD + g * 8 + s * 32];

  const int* ninK = nin + bk * Lpairs;
  const int* noutK = nout + bk * Lpairs;
  const int base0 = chunk * (4 * ITER * 16) + wave * (ITER * 16);
  const int MAXB = Lpairs - 16;  // Lpairs % 16 == 0

  // Clamped tile base: out-of-range tiles recompute the last tile (idempotent
  // duplicate writes of identical values). pb(it) == base0+it*16 whenever valid.
#define PB(IT) (((base0 + (IT) * 16) < MAXB) ? (base0 + (IT) * 16) : MAXB)

  // Hist input loads first (independent, drain before the pipeline steady-state).
  int hrow[ITER];
  if (g == 0) {
#pragma unroll
    for (int it = 0; it < ITER; ++it) hrow[it] = noutK[PB(it) + r];
  }

  // Index pipeline: depth 2. Feature pipeline: depth 1.
  int arowA = ninK[PB(0) + r];
  int arowB = ninK[PB(1) + r];
  f32x4 fA0, fA1, fA2, fA3;
  {
    const float* ap = feat + (size_t)arowA * 64 + g * 8;
    fA0 = *(const f32x4*)(ap);
    fA1 = *(const f32x4*)(ap + 4);
    fA2 = *(const f32x4*)(ap + 32);
    fA3 = *(const f32x4*)(ap + 36);
  }

#pragma unroll
  for (int it = 0; it < ITER; ++it) {
    int arowN = 0;
    if (it + 2 < ITER) arowN = ninK[PB(it + 2) + r];
    f32x4 fB0, fB1, fB2, fB3;
    if (it + 1 < ITER) {
      const float* ap = feat + (size_t)arowB * 64 + g * 8;
      fB0 = *(const f32x4*)(ap);
      fB1 = *(const f32x4*)(ap + 4);
      fB2 = *(const f32x4*)(ap + 32);
      fB3 = *(const f32x4*)(ap + 36);
    }

    bf16x8 a0, a1;
#pragma unroll
    for (int j = 0; j < 4; ++j) {
      a0[j] = (__bf16)fA0[j];
      a0[j + 4] = (__bf16)fA1[j];
      a1[j] = (__bf16)fA2[j];
      a1[j + 4] = (__bf16)fA3[j];
    }

    f32x4 acc[4] = {f32x4{0.f, 0.f, 0.f, 0.f}, f32x4{0.f, 0.f, 0.f, 0.f},
                    f32x4{0.f, 0.f, 0.f, 0.f}, f32x4{0.f, 0.f, 0.f, 0.f}};
#pragma unroll
    for (int t = 0; t < 4; ++t) {
      acc[t] = __builtin_amdgcn_mfma_f32_16x16x32_bf16(wfrag[0][t], a0, acc[t], 0, 0, 0);
      acc[t] = __builtin_amdgcn_mfma_f32_16x16x32_bf16(wfrag[1][t], a1, acc[t], 0, 0, 0);
    }

    // D layout: col=lane&15 -> pair r, row=g*4+reg -> channel t*16+g*4+reg
    __bf16* vp = vals + ((size_t)bk * Lpairs + PB(it) + r) * 64;
#pragma unroll
    for (int t = 0; t < 4; ++t) {
      bf16x4 v;
#pragma unroll
      for (int reg = 0; reg < 4; ++reg) v[reg] = (__bf16)acc[t][reg];
      *(bf16x4*)(vp + t * 16 + g * 4) = v;  // 8B store
    }

    // rotate pipeline
    if (it + 1 < ITER) {
      fA0 = fB0; fA1 = fB1; fA2 = fB2; fA3 = fB3;
      arowA = arowB;
      arowB = arowN;
    }
  }

  // Fused histogram at END of wave: atomic latency overlaps other waves' compute,
  // and never sits ahead of compute loads in the vmcnt queue.
  if (g == 0) {
#pragma unroll
    for (int it = 0; it < ITER; ++it) {
      if (base0 + it * 16 < Lpairs) {  // exactly-once predicate (unclamped)
        int rank = atomicAdd(&counts[hrow[it] << cshift], 1);
        if (rank < CAP)
          slots[hrow[it] * CAP + rank] = bk * Lpairs + base0 + it * 16 + r;
      }
    }
  }
#undef PB
}

// ---- K3: per-row segmented reduce, 4-deep ILP ----
__global__ __launch_bounds__(256) void k3_reduce(const __bf16* __restrict__ vals,
                                                 const int* __restrict__ counts,
                                                 const int* __restrict__ slots,
                                                 float* __restrict__ out, int Nrows,
                                                 int cshift) {
  const int wid = (blockIdx.x * 256 + threadIdx.x) >> 6;
  const int lane = threadIdx.x & 63;
  if (wid >= Nrows) return;
  int cnt = counts[wid << cshift];
  cnt = cnt > CAP ? CAP : cnt;
  int myslot = (lane < cnt) ? slots[wid * CAP + lane] : 0;
  float acc = 0.f;
  int j = 0;
  for (; j + 3 < cnt; j += 4) {
    int s0 = __shfl(myslot, j);
    int s1 = __shfl(myslot, j + 1);
    int s2 = __shfl(myslot, j + 2);
    int s3 = __shfl(myslot, j + 3);
    float v0 = (float)vals[(size_t)s0 * 64 + lane];
    float v1 = (float)vals[(size_t)s1 * 64 + lane];
    float v2 = (float)vals[(size_t)s2 * 64 + lane];
    float v3 = (float)vals[(size_t)s3 * 64 + lane];
    acc += v0; acc += v1; acc += v2; acc += v3;
  }
  for (; j < cnt; ++j) {
    int s0 = __shfl(myslot, j);
    acc += (float)vals[(size_t)s0 * 64 + lane];
  }
  out[(size_t)wid * 64 + lane] = acc;
}

// ---- Fallback: atomic kernel (used only if ws too small) ----
template <int ITER>
__global__ __launch_bounds__(256) void spconv_atomic_kernel(
    const float* __restrict__ feat, const float* __restrict__ kern,
    const int* __restrict__ nin, const int* __restrict__ nout,
    float* __restrict__ out, int Lpairs, int blocksPerK) {
  __shared__ __bf16 ldsBT[64 * WPAD];
  const int bk = blockIdx.x / blocksPerK;
  const int chunk = blockIdx.x % blocksPerK;
  const float* kb = kern + bk * 4096;
  for (int idx = threadIdx.x; idx < 4096; idx += 256) {
    int i = idx >> 6, c = idx & 63;
    ldsBT[c * WPAD + i] = (__bf16)kb[idx];
  }
  __syncthreads();
  const int lane = threadIdx.x & 63;
  const int wave = threadIdx.x >> 6;
  const int r = lane & 15, g = lane >> 4;
  bf16x8 bfrag[2][4];
#pragma unroll
  for (int s = 0; s < 2; ++s)
#pragma unroll
    for (int t = 0; t < 4; ++t)
      bfrag[s][t] = *(const bf16x8*)&ldsBT[(t * 16 + r) * WPAD + g * 8 + s * 32];
  const int* ninK = nin + bk * Lpairs;
  const int* noutK = nout + bk * Lpairs;
  const int base0 = chunk * (4 * ITER * 16) + wave * (ITER * 16);
  for (int it = 0; it < ITER; ++it) {
    const int base = base0 + it * 16;
    if (base >= Lpairs) break;
    const int arow = ninK[base + r];
    const float* ap = feat + (size_t)arow * 64 + g * 8;
    f32x4 f0 = *(const f32x4*)(ap);
    f32x4 f1 = *(const f32x4*)(ap + 4);
    f32x4 f2 = *(const f32x4*)(ap + 32);
    f32x4 f3 = *(const f32x4*)(ap + 36);
    bf16x8 a0, a1;
#pragma unroll
    for (int j = 0; j < 4; ++j) {
      a0[j] = (__bf16)f0[j];
      a0[j + 4] = (__bf16)f1[j];
      a1[j] = (__bf16)f2[j];
      a1[j + 4] = (__bf16)f3[j];
    }
    f32x4 acc[4] = {f32x4{0.f, 0.f, 0.f, 0.f}, f32x4{0.f, 0.f, 0.f, 0.f},
                    f32x4{0.f, 0.f, 0.f, 0.f}, f32x4{0.f, 0.f, 0.f, 0.f}};
#pragma unroll
    for (int t = 0; t < 4; ++t) {
      acc[t] = __builtin_amdgcn_mfma_f32_16x16x32_bf16(a0, bfrag[0][t], acc[t], 0, 0, 0);
      acc[t] = __builtin_amdgcn_mfma_f32_16x16x32_bf16(a1, bfrag[1][t], acc[t], 0, 0, 0);
    }
    int orow[4];
#pragma unroll
    for (int reg = 0; reg < 4; ++reg) orow[reg] = noutK[base + g * 4 + reg];
#pragma unroll
    for (int t = 0; t < 4; ++t)
#pragma unroll
      for (int reg = 0; reg < 4; ++reg)
        atomicAdd(out + (size_t)orow[reg] * 64 + t * 16 + r, acc[t][reg]);
  }
}

extern "C" void kernel_launch(void* const* d_in, const int* in_sizes, int n_in,
                              void* d_out, int out_size, void* d_ws, size_t ws_size,
                              hipStream_t stream) {
  const float* feat = (const float*)d_in[0];
  const float* kern = (const float*)d_in[1];
  const int* nin = (const int*)d_in[2];
  const int* nout = (const int*)d_in[3];
  float* out = (float*)d_out;

  const int total = in_sizes[2];        // 27*L pairs
  const int Lpairs = total / KOFF;      // 50000
  const int Nrows = out_size / 64;      // 100000

  constexpr int ITER = 8;
  const int pairsPerBlock = 4 * ITER * 16;  // 512
  const int blocksPerK = (Lpairs + pairsPerBlock - 1) / pairsPerBlock;

  // ws layout: counts (padded by 1<<cshift ints per row to kill coherent-point
  // line contention), slots, vals. Pick the largest cshift that fits.
  int cshift = -1;
  size_t countsBytes = 0, slotsOff = 0, valsOff = 0;
  for (int cs = 4; cs >= 0; cs -= 2) {
    size_t cb = ((size_t)Nrows << cs) * 4;
    size_t so = (cb + 255) & ~(size_t)255;
    size_t vo = ((so + (size_t)Nrows * CAP * 4) + 255) & ~(size_t)255;
    size_t needed = vo + (size_t)total * 64 * 2;
    if (ws_size >= needed) { cshift = cs; countsBytes = cb; slotsOff = so; valsOff = vo; break; }
  }

  if (cshift >= 0) {
    int* counts = (int*)d_ws;
    int* slots = (int*)((char*)d_ws + slotsOff);
    __bf16* vals = (__bf16*)((char*)d_ws + valsOff);

    hipMemsetAsync(counts, 0, countsBytes, stream);
    k2_gemm_hist<ITER><<<KOFF * blocksPerK, 256, 0, stream>>>(
        feat, kern, nin, nout, counts, slots, vals, Lpairs, blocksPerK, cshift);
    k3_reduce<<<(Nrows * 64 + 255) / 256, 256, 0, stream>>>(vals, counts, slots,
                                                            out, Nrows, cshift);
  } else {
    hipMemsetAsync(d_out, 0, (size_t)out_size * sizeof(float), stream);
    spconv_atomic_kernel<ITER><<<KOFF * blocksPerK, 256, 0, stream>>>(
        feat, kern, nin, nout, out, Lpairs, blocksPerK);
  }
}